// Round 13
// baseline (257.158 us; speedup 1.0000x reference)
//
#include <hip/hip_runtime.h>
#include <hip/hip_bf16.h>

typedef __attribute__((ext_vector_type(8))) short short8;
typedef __attribute__((ext_vector_type(4))) float f32x4;
typedef __attribute__((ext_vector_type(16))) float f32x16;
typedef __attribute__((ext_vector_type(4))) unsigned uint4v;

#define NMODEL 24
#define DIN    495
#define KP     512
#define HID    64
#define NLAY   5

__device__ __forceinline__ short bf16r(float f) {
    unsigned u = __float_as_uint(f);
    u += 0x7fffu + ((u >> 16) & 1u);          // round-to-nearest-even
    return (short)(u >> 16);
}
__device__ __forceinline__ float bf16f(short s) {
    return __uint_as_float(((unsigned)(unsigned short)s) << 16);
}
// packed f32->bf16: one VALU op for two elements (gfx950 v_cvt_pk_bf16_f32)
__device__ __forceinline__ unsigned pkbf16(float lo, float hi) {
    unsigned r;
    asm("v_cvt_pk_bf16_f32 %0, %1, %2" : "=v"(r) : "v"(lo), "v"(hi));
    return r;
}
__device__ __forceinline__ f32x16 mfma32(short8 a, short8 b, f32x16 c) {
    return __builtin_amdgcn_mfma_f32_32x32x16_bf16(a, b, c, 0, 0, 0);
}

struct __attribute__((packed, aligned(4))) f4a { float v[4]; };

// ---------------------------------------------------------------------------
// Weight pre-conversion for 32x32x16 MFMA fragments.
// A-operand layout (verified family): lane holds A[row=lane&31][k=8*(lane>>5)+t].
//   wib32[m][ks 32][T 2][lane 64][t 8] = W_in[kg][32T+(lane&31)], kg=16ks+8(lane>>5)+t
//   whb32[m][l][s 4][T 2][lane 64][t 8] = W_h[m][l][pk][32T+(lane&31)]
//     pk = 32*(t>>2)+(t&3)+8*s+4*(lane>>5)  — the permutation that makes the
//     previous layer's D fragments (col=lane&31 x-row; hout=(r&3)+8(r>>2)+4h5)
//     feed the next layer's B operand entirely lane-locally.
// ---------------------------------------------------------------------------
__global__ void dg_convert(const float* __restrict__ W_in,
                           const float* __restrict__ W_h,
                           short* __restrict__ wib, short* __restrict__ whb) {
    int idx = blockIdx.x * 256 + threadIdx.x;
    if (idx < NMODEL * 32 * 2 * 64 * 8) {          // 786432
        int t    = idx & 7;
        int lane = (idx >> 3) & 63;
        int T    = (idx >> 9) & 1;
        int ks   = (idx >> 10) & 31;
        int m    = idx >> 15;
        int kg   = ks * 16 + (lane >> 5) * 8 + t;
        int hout = T * 32 + (lane & 31);
        float v  = (kg < DIN) ? W_in[((size_t)m * DIN + kg) * HID + hout] : 0.f;
        wib[idx] = bf16r(v);
    }
    if (idx < NMODEL * NLAY * 4 * 2 * 64 * 8) {    // 491520
        int t    = idx & 7;
        int lane = (idx >> 3) & 63;
        int T    = (idx >> 9) & 1;
        int s    = (idx >> 10) & 3;
        int ml   = idx >> 12;                      // m*5 + l
        int pk   = 32 * (t >> 2) + (t & 3) + 8 * s + 4 * (lane >> 5);
        int hout = T * 32 + (lane & 31);
        whb[idx] = bf16r(W_h[((size_t)ml * HID + pk) * HID + hout]);
    }
}

// ---------------------------------------------------------------------------
// Fused kernel, 32x32x16 MFMA variant. Block = 512 threads (8 waves), 64 rows
// of x in LDS (bf16, XOR-swizzled). Each wave owns a 32-row half-tile and
// runs 6 models; waves PAIRED on model so weight streams merge in L1/L2.
// Per model: proj = 16 ks-pairs x (6 loads + 4 MFMA), hidden = 5 layers x
// 2 s-pairs x (4 loads + 4 MFMA). 104 MFMA/model (was 208 at 16x16x32;
// 2382 vs 2075 TF shape ceiling -> ~13% less MFMA pipe time, ~40% fewer
// hot-loop instructions). acc/hacc = 2 x f32x16 (same 32 regs as before).
// setprio around MFMA clusters (round 11 +2.5%); bias via MFMA C-init.
// 64KB LDS -> 2 blocks/CU -> 16 waves/CU (4/SIMD).
// ---------------------------------------------------------------------------
__global__ __launch_bounds__(512, 4) void dg_main(
    const float* __restrict__ x,
    const short* __restrict__ wib, const short* __restrict__ whb,
    const float* __restrict__ b_in, const float* __restrict__ b_h,
    const float* __restrict__ W_out, const float* __restrict__ b_out,
    float* __restrict__ out) {

    __shared__ short xs[64 * KP];            // 64 KB

    const int tid  = threadIdx.x;
    const int lane = tid & 63;
    const int w    = tid >> 6;               // wave 0..7
    const int r32  = lane & 31;              // x-row within the 32-row half
    const int h5   = lane >> 5;              // lane half (k-octet / hout+4)
    const int rowbase = blockIdx.x * 64;
    const int pair = w >> 1;                 // 0..3: model group
    const int hf   = w & 1;                  // row half within the tile
    const int rbase = hf * 32;

    // ---- stage x tile -> LDS as bf16, swizzled, zero-padded k>=495 ----
    for (int i = 0; i < 8; ++i) {
        int r  = i * 8 + w;
        int k0 = lane * 8;
        const float* xr = x + (size_t)(rowbase + r) * DIN + k0;
        uint4v vw;
        if (k0 + 8 <= DIN) {                 // lanes 0..60: fast vector path
            f4a a = *(const f4a*)xr;
            f4a b = *(const f4a*)(xr + 4);
            vw[0] = pkbf16(a.v[0], a.v[1]);
            vw[1] = pkbf16(a.v[2], a.v[3]);
            vw[2] = pkbf16(b.v[0], b.v[1]);
            vw[3] = pkbf16(b.v[2], b.v[3]);
        } else {                             // lanes 61..63: guarded tail
            float f[8];
#pragma unroll
            for (int j = 0; j < 8; ++j) f[j] = (k0 + j < DIN) ? xr[j] : 0.f;
            vw[0] = pkbf16(f[0], f[1]);
            vw[1] = pkbf16(f[2], f[3]);
            vw[2] = pkbf16(f[4], f[5]);
            vw[3] = pkbf16(f[6], f[7]);
        }
        int byte = (r * (KP * 2) + k0 * 2) ^ ((r & 7) << 4);
        *(short8*)((char*)xs + byte) = __builtin_bit_cast(short8, vw);
    }
    __syncthreads();

    const int xrow  = rbase + r32;
    const int xbase = xrow * (KP * 2);
    const int xswz  = (xrow & 7) << 4;

    // ---- 6 models per wave (paired across row halves), no further sync ----
#pragma unroll 1
    for (int mi = 0; mi < 6; ++mi) {
        const int m = pair * 6 + mi;

        // ---------------- input projection: D[hout 64][row 32], K = 512
        // bias -> C-init: acc{T} reg r holds hout = 32T + (r&3)+8(r>>2)+4h5
        const float* bi = b_in + m * HID;
        f32x16 acc0, acc1;
#pragma unroll
        for (int q = 0; q < 4; ++q) {
            f32x4 b0 = *(const f32x4*)(bi + 8 * q + 4 * h5);
            f32x4 b1 = *(const f32x4*)(bi + 32 + 8 * q + 4 * h5);
#pragma unroll
            for (int j = 0; j < 4; ++j) {
                acc0[4 * q + j] = b0[j];
                acc1[4 * q + j] = b1[j];
            }
        }

        const short8* wA = (const short8*)wib + (size_t)m * 4096;
#pragma unroll 2
        for (int kp = 0; kp < 16; ++kp) {
            const int ks0 = 2 * kp, ks1 = 2 * kp + 1;
            short8 a00 = wA[(ks0 * 2 + 0) * 64 + lane];
            short8 a01 = wA[(ks0 * 2 + 1) * 64 + lane];
            short8 a10 = wA[(ks1 * 2 + 0) * 64 + lane];
            short8 a11 = wA[(ks1 * 2 + 1) * 64 + lane];
            short8 b0 = *(const short8*)((const char*)xs +
                          ((xbase + ks0 * 32 + h5 * 16) ^ xswz));
            short8 b1 = *(const short8*)((const char*)xs +
                          ((xbase + ks1 * 32 + h5 * 16) ^ xswz));
            __builtin_amdgcn_s_setprio(1);
            acc0 = mfma32(a00, b0, acc0);
            acc1 = mfma32(a01, b0, acc1);
            acc0 = mfma32(a10, b1, acc0);
            acc1 = mfma32(a11, b1, acc1);
            __builtin_amdgcn_s_setprio(0);
        }

        // pack h0 -> B-fragments (kept for the residual)
        // frag[s] slot t: T=t>>2, r=4s+(t&3)  (matches pk baked in whb)
        short8 h0b[4], hc[4];
#pragma unroll
        for (int s = 0; s < 4; ++s) {
            uint4v wv;
            wv[0] = pkbf16(acc0[4 * s + 0], acc0[4 * s + 1]);
            wv[1] = pkbf16(acc0[4 * s + 2], acc0[4 * s + 3]);
            wv[2] = pkbf16(acc1[4 * s + 0], acc1[4 * s + 1]);
            wv[3] = pkbf16(acc1[4 * s + 2], acc1[4 * s + 3]);
            h0b[s] = __builtin_bit_cast(short8, wv);
            hc[s]  = h0b[s];
        }

        // ---------------- 5 hidden layers, all in registers
        const short8* wH = (const short8*)whb + (size_t)m * 2560;
        f32x16 ha0, ha1;
#pragma unroll 1
        for (int l = 0; l < NLAY; ++l) {
            const float* bh = b_h + (size_t)(m * NLAY + l) * HID;
#pragma unroll
            for (int q = 0; q < 4; ++q) {
                f32x4 b0 = *(const f32x4*)(bh + 8 * q + 4 * h5);
                f32x4 b1 = *(const f32x4*)(bh + 32 + 8 * q + 4 * h5);
#pragma unroll
                for (int j = 0; j < 4; ++j) {
                    ha0[4 * q + j] = b0[j];
                    ha1[4 * q + j] = b1[j];
                }
            }
#pragma unroll
            for (int sp = 0; sp < 2; ++sp) {
                const int s0 = 2 * sp, s1 = 2 * sp + 1;
                short8 a00 = wH[(size_t)((l * 4 + s0) * 2 + 0) * 64 + lane];
                short8 a01 = wH[(size_t)((l * 4 + s0) * 2 + 1) * 64 + lane];
                short8 a10 = wH[(size_t)((l * 4 + s1) * 2 + 0) * 64 + lane];
                short8 a11 = wH[(size_t)((l * 4 + s1) * 2 + 1) * 64 + lane];
                __builtin_amdgcn_s_setprio(1);
                ha0 = mfma32(a00, hc[s0], ha0);
                ha1 = mfma32(a01, hc[s0], ha1);
                ha0 = mfma32(a10, hc[s1], ha0);
                ha1 = mfma32(a11, hc[s1], ha1);
                __builtin_amdgcn_s_setprio(0);
            }
            // relu (bias already in accumulator)
#pragma unroll
            for (int e = 0; e < 16; ++e) {
                ha0[e] = fmaxf(ha0[e], 0.f);
                ha1[e] = fmaxf(ha1[e], 0.f);
            }
            if (l != NLAY - 1) {
#pragma unroll
                for (int s = 0; s < 4; ++s) {
                    uint4v wv;
                    wv[0] = pkbf16(ha0[4 * s + 0], ha0[4 * s + 1]);
                    wv[1] = pkbf16(ha0[4 * s + 2], ha0[4 * s + 3]);
                    wv[2] = pkbf16(ha1[4 * s + 0], ha1[4 * s + 1]);
                    wv[3] = pkbf16(ha1[4 * s + 2], ha1[4 * s + 3]);
                    hc[s] = __builtin_bit_cast(short8, wv);
                }
            }
        }

        // ---------------- residual: h += h0 (h0(T,r) = h0b[r>>2][4T+(r&3)])
#pragma unroll
        for (int r = 0; r < 16; ++r) {
            ha0[r] += bf16f(h0b[r >> 2][r & 3]);
            ha1[r] += bf16f(h0b[r >> 2][4 + (r & 3)]);
        }

        // ---------------- head: dot(h, W_out) + b_out, tanh, store
        const float* wo = W_out + m * HID;
        float s = 0.f;
#pragma unroll
        for (int q = 0; q < 4; ++q) {
            f32x4 w0 = *(const f32x4*)(wo + 8 * q + 4 * h5);
            f32x4 w1 = *(const f32x4*)(wo + 32 + 8 * q + 4 * h5);
#pragma unroll
            for (int j = 0; j < 4; ++j) {
                s += ha0[4 * q + j] * w0[j];
                s += ha1[4 * q + j] * w1[j];
            }
        }
        s += __shfl_xor(s, 32);                    // combine the two h5 halves
        s += b_out[m];
        float e = __expf(2.f * s);                 // overflow-safe tanh
        float o = 1.f - 2.f / (e + 1.f);
        if (h5 == 0)
            out[(size_t)(rowbase + rbase + r32) * NMODEL + m] = o;
    }
}

extern "C" void kernel_launch(void* const* d_in, const int* in_sizes, int n_in,
                              void* d_out, int out_size, void* d_ws, size_t ws_size,
                              hipStream_t stream) {
    const float* x     = (const float*)d_in[0];
    const float* W_in  = (const float*)d_in[1];
    const float* b_in  = (const float*)d_in[2];
    const float* W_h   = (const float*)d_in[3];
    const float* b_h   = (const float*)d_in[4];
    const float* W_out = (const float*)d_in[5];
    const float* b_out = (const float*)d_in[6];
    float* out = (float*)d_out;

    short* wib = (short*)d_ws;                       // 786432 bf16 = 1.5 MB
    short* whb = wib + NMODEL * 32 * 2 * 64 * 8;     // 491520 bf16 = 0.94 MB

    const int N = in_sizes[0] / DIN;                 // 65536

    dg_convert<<<3072, 256, 0, stream>>>(W_in, W_h, wib, whb);
    dg_main<<<N / 64, 512, 0, stream>>>(x, wib, whb, b_in, b_h, W_out, b_out, out);
}

// Round 14
// 225.917 us; speedup vs baseline: 1.1383x; 1.1383x over previous
//
#include <hip/hip_runtime.h>
#include <hip/hip_bf16.h>

typedef __attribute__((ext_vector_type(8))) short short8;
typedef __attribute__((ext_vector_type(4))) float f32x4;
typedef __attribute__((ext_vector_type(4))) unsigned uint4v;

#define NMODEL 24
#define DIN    495
#define KP     512
#define HID    64
#define NLAY   5

__device__ __forceinline__ short bf16r(float f) {
    unsigned u = __float_as_uint(f);
    u += 0x7fffu + ((u >> 16) & 1u);          // round-to-nearest-even
    return (short)(u >> 16);
}
__device__ __forceinline__ float bf16f(short s) {
    return __uint_as_float(((unsigned)(unsigned short)s) << 16);
}
// packed f32->bf16: one VALU op for two elements (gfx950 v_cvt_pk_bf16_f32)
__device__ __forceinline__ unsigned pkbf16(float lo, float hi) {
    unsigned r;
    asm("v_cvt_pk_bf16_f32 %0, %1, %2" : "=v"(r) : "v"(lo), "v"(hi));
    return r;
}
// pack two f32x4 fragments into one MFMA B-fragment (short8)
__device__ __forceinline__ short8 pack2(f32x4 a, f32x4 b) {
    uint4v w;
    w[0] = pkbf16(a[0], a[1]);
    w[1] = pkbf16(a[2], a[3]);
    w[2] = pkbf16(b[0], b[1]);
    w[3] = pkbf16(b[2], b[3]);
    return __builtin_bit_cast(short8, w);
}
// write a D-fragment (4 consecutive hout at col..col+3) into the swizzled h-buf
__device__ __forceinline__ void wr_h(char* hb, int row, int col, f32x4 v) {
    unsigned d0 = pkbf16(v[0], v[1]);
    unsigned d1 = pkbf16(v[2], v[3]);
    int byte = (row * 128 + col * 2) ^ ((row & 7) << 4);
    unsigned long long q = (unsigned long long)d0 |
                           ((unsigned long long)d1 << 32);
    *(unsigned long long*)(hb + byte) = q;
}

struct __attribute__((packed, aligned(4))) f4a { float v[4]; };

// ---------------------------------------------------------------------------
// Weight pre-conversion, NATURAL k-order (the h tensor now round-trips LDS,
// which re-buckets the contraction axis — no baked permutation needed).
//   wib[m][kb 64][hout 64][t 8] = W_in[m][kb*8+t][hout]   (k padded 495->512)
//   whb[m][l][kb 8][hout 64][t 8] = W_h[m][l][kb*8+t][hout]
// ---------------------------------------------------------------------------
__global__ void dg_convert(const float* __restrict__ W_in,
                           const float* __restrict__ W_h,
                           short* __restrict__ wib, short* __restrict__ whb) {
    int idx = blockIdx.x * 256 + threadIdx.x;
    if (idx < NMODEL * 64 * HID * 8) {
        int t    = idx & 7;
        int hout = (idx >> 3) & 63;
        int kb   = (idx >> 9) & 63;
        int m    = idx >> 15;
        int k    = kb * 8 + t;
        float v  = (k < DIN) ? W_in[((size_t)m * DIN + k) * HID + hout] : 0.f;
        wib[idx] = bf16r(v);
    }
    if (idx < NMODEL * NLAY * 8 * HID * 8) {
        int t    = idx & 7;
        int hout = (idx >> 3) & 63;
        int kb   = (idx >> 9) & 7;
        int ml   = idx >> 12;          // m*5 + l
        int k    = kb * 8 + t;
        whb[idx] = bf16r(W_h[((size_t)ml * HID + k) * HID + hout]);
    }
}

// ---------------------------------------------------------------------------
// Fused kernel, hout-split wave pairs. Block = 1024 threads (16 waves =
// 8 pairs), 64-row x tile. Wave (pair p, hh) computes 64 rows x 32 hout
// (acc 2x4 frags, 32 regs) for 3 models -> per-wave VMEM weight traffic
// 156 KB vs 624 KB in the row-split design (4x cut — the measured limiter
// was VMEM latency/queueing from 16 waves streaming 104 KB/model each).
// Layer hand-off through a per-pair 8 KB LDS h-buffer (XOR-swizzled like
// xs); natural-k weights. LDS = 64K xs + 64K hbuf + 4K pbuf = 132 KB
// dynamic -> 1 block/CU, 16 waves/CU (4/SIMD) — same occupancy as before.
// ---------------------------------------------------------------------------
__global__ __launch_bounds__(1024, 4) void dg_main(
    const float* __restrict__ x,
    const short* __restrict__ wib, const short* __restrict__ whb,
    const float* __restrict__ b_in, const float* __restrict__ b_h,
    const float* __restrict__ W_out, const float* __restrict__ b_out,
    float* __restrict__ out) {

    extern __shared__ char lds[];
    short* xs = (short*)lds;                             // [64][512] bf16, 64 KB

    const int tid  = threadIdx.x;
    const int lane = tid & 63;
    const int w    = tid >> 6;               // wave 0..15
    const int lrow = lane & 15;
    const int g    = lane >> 4;              // lane group 0..3
    const int rowbase = blockIdx.x * 64;
    const int pairI = w >> 1;                // 0..7
    const int hh    = w & 1;                 // hout half
    char*  hb = lds + 65536 + pairI * 8192;  // [64 rows][64 hout] bf16, swz
    float* pb = (float*)(lds + 131072 + pairI * 512);    // [2][64] partials

    // ---- stage x tile -> LDS as bf16, swizzled, zero-padded k>=495 ----
    for (int i = 0; i < 4; ++i) {
        int r  = i * 16 + w;
        int k0 = lane * 8;
        const float* xr = x + (size_t)(rowbase + r) * DIN + k0;
        uint4v vw;
        if (k0 + 8 <= DIN) {                 // lanes 0..60: fast vector path
            f4a a = *(const f4a*)xr;
            f4a b = *(const f4a*)(xr + 4);
            vw[0] = pkbf16(a.v[0], a.v[1]);
            vw[1] = pkbf16(a.v[2], a.v[3]);
            vw[2] = pkbf16(b.v[0], b.v[1]);
            vw[3] = pkbf16(b.v[2], b.v[3]);
        } else {                             // lanes 61..63: guarded tail
            float f[8];
#pragma unroll
            for (int j = 0; j < 8; ++j) f[j] = (k0 + j < DIN) ? xr[j] : 0.f;
            vw[0] = pkbf16(f[0], f[1]);
            vw[1] = pkbf16(f[2], f[3]);
            vw[2] = pkbf16(f[4], f[5]);
            vw[3] = pkbf16(f[6], f[7]);
        }
        int byte = (r * (KP * 2) + k0 * 2) ^ ((r & 7) << 4);
        *(short8*)((char*)xs + byte) = __builtin_bit_cast(short8, vw);
    }
    __syncthreads();

    // ---- 3 models per pair; pairs independent, barriers block-lockstep ----
#pragma unroll 1
    for (int mi = 0; mi < 3; ++mi) {
        const int m = pairI * 3 + mi;

        // -------- input projection: D[32 hout (this half)][64 rows], K=512
        const float* bi = b_in + m * HID + hh * 32;
        f32x4 acc[2][4];                      // [icf][rf]
#pragma unroll
        for (int icf = 0; icf < 2; ++icf) {
            f32x4 bv = *(const f32x4*)(bi + icf * 16 + g * 4);
#pragma unroll
            for (int rf = 0; rf < 4; ++rf) acc[icf][rf] = bv;
        }

        const short8* wA = (const short8*)wib + (size_t)m * 4096;
#pragma unroll 2
        for (int skt = 0; skt < 16; ++skt) {
            const int kb = skt * 4 + g;
            short8 afr[2], bfr[4];
#pragma unroll
            for (int icf = 0; icf < 2; ++icf)
                afr[icf] = wA[(size_t)kb * 64 + hh * 32 + icf * 16 + lrow];
#pragma unroll
            for (int rf = 0; rf < 4; ++rf) {
                int r = rf * 16 + lrow;
                int byte = (r * (KP * 2) + skt * 64 + g * 16) ^ ((r & 7) << 4);
                bfr[rf] = *(const short8*)((const char*)xs + byte);
            }
            __builtin_amdgcn_s_setprio(1);
#pragma unroll
            for (int icf = 0; icf < 2; ++icf)
#pragma unroll
                for (int rf = 0; rf < 4; ++rf)
                    acc[icf][rf] = __builtin_amdgcn_mfma_f32_16x16x32_bf16(
                        afr[icf], bfr[rf], acc[icf][rf], 0, 0, 0);
            __builtin_amdgcn_s_setprio(0);
        }

        // keep h0 for the residual; publish h0 to the pair's h-buf
        short8 h0b[4];                        // [rf]; slot icf*4+j
#pragma unroll
        for (int rf = 0; rf < 4; ++rf)
            h0b[rf] = pack2(acc[0][rf], acc[1][rf]);
#pragma unroll
        for (int icf = 0; icf < 2; ++icf)
#pragma unroll
            for (int rf = 0; rf < 4; ++rf)
                wr_h(hb, rf * 16 + lrow, hh * 32 + icf * 16 + g * 4,
                     acc[icf][rf]);
        __syncthreads();                      // h0 visible to both halves

        // -------- 5 hidden layers; input h from LDS, output via LDS (l<4)
        const short8* wHm = (const short8*)whb + (size_t)m * 2560;
        f32x4 ha[2][4];
#pragma unroll 1
        for (int l = 0; l < NLAY; ++l) {
            const float* bh = b_h + (size_t)(m * NLAY + l) * HID + hh * 32;
#pragma unroll
            for (int icf = 0; icf < 2; ++icf) {
                f32x4 bv = *(const f32x4*)(bh + icf * 16 + g * 4);
#pragma unroll
                for (int rf = 0; rf < 4; ++rf) ha[icf][rf] = bv;
            }
#pragma unroll
            for (int s = 0; s < 2; ++s) {
                const int kb = 4 * s + g;
                short8 afr[2], bfr[4];
#pragma unroll
                for (int icf = 0; icf < 2; ++icf)
                    afr[icf] = wHm[(size_t)(l * 8 + kb) * 64 +
                                   hh * 32 + icf * 16 + lrow];
#pragma unroll
                for (int rf = 0; rf < 4; ++rf) {
                    int r = rf * 16 + lrow;
                    int byte = (r * 128 + kb * 16) ^ ((r & 7) << 4);
                    bfr[rf] = *(const short8*)(hb + byte);
                }
                __builtin_amdgcn_s_setprio(1);
#pragma unroll
                for (int icf = 0; icf < 2; ++icf)
#pragma unroll
                    for (int rf = 0; rf < 4; ++rf)
                        ha[icf][rf] = __builtin_amdgcn_mfma_f32_16x16x32_bf16(
                            afr[icf], bfr[rf], ha[icf][rf], 0, 0, 0);
                __builtin_amdgcn_s_setprio(0);
            }
            // relu (bias already in accumulator)
#pragma unroll
            for (int icf = 0; icf < 2; ++icf)
#pragma unroll
                for (int rf = 0; rf < 4; ++rf)
#pragma unroll
                    for (int j = 0; j < 4; ++j)
                        ha[icf][rf][j] = fmaxf(ha[icf][rf][j], 0.f);
            if (l != NLAY - 1) {
                __syncthreads();              // all reads of h_l done
#pragma unroll
                for (int icf = 0; icf < 2; ++icf)
#pragma unroll
                    for (int rf = 0; rf < 4; ++rf)
                        wr_h(hb, rf * 16 + lrow, hh * 32 + icf * 16 + g * 4,
                             ha[icf][rf]);
                __syncthreads();              // h_{l+1} visible
            }
        }

        // -------- residual: h += h0 (bf16-rounded, ~2^-9 rel err)
#pragma unroll
        for (int icf = 0; icf < 2; ++icf)
#pragma unroll
            for (int rf = 0; rf < 4; ++rf)
#pragma unroll
                for (int j = 0; j < 4; ++j)
                    ha[icf][rf][j] += bf16f(h0b[rf][icf * 4 + j]);

        // -------- head: per-half partial, combine across the pair via LDS
        const float* wo = W_out + m * HID + hh * 32;
        float hp[4];
#pragma unroll
        for (int rf = 0; rf < 4; ++rf) {
            float s = 0.f;
#pragma unroll
            for (int icf = 0; icf < 2; ++icf) {
                f32x4 wv = *(const f32x4*)(wo + icf * 16 + g * 4);
#pragma unroll
                for (int j = 0; j < 4; ++j)
                    s += ha[icf][rf][j] * wv[j];
            }
            s += __shfl_xor(s, 16);
            s += __shfl_xor(s, 32);
            hp[rf] = s;
        }
        if (g == 0) {
#pragma unroll
            for (int rf = 0; rf < 4; ++rf)
                pb[hh * 64 + rf * 16 + lrow] = hp[rf];
        }
        __syncthreads();                      // partials ready (also guards hb)
        {
            int r = hh * 32 + (lane & 31);
            if (lane < 32) {
                float s = pb[r] + pb[64 + r] + b_out[m];
                float e = __expf(2.f * s);    // overflow-safe tanh
                float o = 1.f - 2.f / (e + 1.f);
                out[(size_t)(rowbase + r) * NMODEL + m] = o;
            }
        }
        __syncthreads();                      // pbuf/hbuf reusable next model
    }
}

extern "C" void kernel_launch(void* const* d_in, const int* in_sizes, int n_in,
                              void* d_out, int out_size, void* d_ws, size_t ws_size,
                              hipStream_t stream) {
    const float* x     = (const float*)d_in[0];
    const float* W_in  = (const float*)d_in[1];
    const float* b_in  = (const float*)d_in[2];
    const float* W_h   = (const float*)d_in[3];
    const float* b_h   = (const float*)d_in[4];
    const float* W_out = (const float*)d_in[5];
    const float* b_out = (const float*)d_in[6];
    float* out = (float*)d_out;

    short* wib = (short*)d_ws;                       // 24*4096 short8 = 1.5 MB
    short* whb = wib + NMODEL * 64 * HID * 8;        // 24*2560 short8 = 0.94 MB

    const int N = in_sizes[0] / DIN;                 // 65536
    const int LDS_BYTES = 65536 + 65536 + 4096;      // xs + hbuf + pbuf = 132 KB

    hipFuncSetAttribute((const void*)dg_main,
                        hipFuncAttributeMaxDynamicSharedMemorySize, LDS_BYTES);

    dg_convert<<<3072, 256, 0, stream>>>(W_in, W_h, wib, whb);
    dg_main<<<N / 64, 1024, LDS_BYTES, stream>>>(x, wib, whb, b_in, b_h,
                                                 W_out, b_out, out);
}

// Round 15
// 218.213 us; speedup vs baseline: 1.1785x; 1.0353x over previous
//
#include <hip/hip_runtime.h>
#include <hip/hip_bf16.h>

typedef __attribute__((ext_vector_type(8))) short short8;
typedef __attribute__((ext_vector_type(4))) float f32x4;
typedef __attribute__((ext_vector_type(4))) unsigned uint4v;

#define NMODEL 24
#define DIN    495
#define KP     512
#define HID    64
#define NLAY   5
#define CHUNKS 26                    // 16 proj + 10 hidden, 4096 B each
#define MBLOB  (CHUNKS * 4096)       // bytes per model in the weight blob

__device__ __forceinline__ short bf16r(float f) {
    unsigned u = __float_as_uint(f);
    u += 0x7fffu + ((u >> 16) & 1u);
    return (short)(u >> 16);
}
__device__ __forceinline__ float bf16f(short s) {
    return __uint_as_float(((unsigned)(unsigned short)s) << 16);
}
__device__ __forceinline__ unsigned pkbf16(float lo, float hi) {
    unsigned r;
    asm("v_cvt_pk_bf16_f32 %0, %1, %2" : "=v"(r) : "v"(lo), "v"(hi));
    return r;
}
__device__ __forceinline__ short8 pack2(f32x4 a, f32x4 b) {
    uint4v w;
    w[0] = pkbf16(a[0], a[1]);
    w[1] = pkbf16(a[2], a[3]);
    w[2] = pkbf16(b[0], b[1]);
    w[3] = pkbf16(b[2], b[3]);
    return __builtin_bit_cast(short8, w);
}

struct __attribute__((packed, aligned(4))) f4a { float v[4]; };

// asm weight-chunk machinery: 4x global_load_dwordx4, counted vmcnt.
// "=v" outputs are allocator-pinned VGPRs (cannot demote to scratch).
#define GLD(dst, p, OFFSTR) \
    asm volatile("global_load_dwordx4 %0, %1, off offset:" OFFSTR \
                 : "=v"(dst) : "v"(p) : "memory")
#define ISSUE4(n, p) { GLD(n##0, p, "0");   GLD(n##1, p, "256"); \
                       GLD(n##2, p, "512"); GLD(n##3, p, "768"); }
#define VW4 { asm volatile("s_waitcnt vmcnt(4)" ::: "memory"); \
              __builtin_amdgcn_sched_barrier(0); }
#define MF(wv, b, c) __builtin_amdgcn_mfma_f32_16x16x32_bf16( \
                         __builtin_bit_cast(short8, wv), b, c, 0, 0, 0)
#define MM8(n, b0, b1) { \
    __builtin_amdgcn_s_setprio(1); \
    acc[0][0] = MF(n##0, b0, acc[0][0]); acc[0][1] = MF(n##0, b1, acc[0][1]); \
    acc[1][0] = MF(n##1, b0, acc[1][0]); acc[1][1] = MF(n##1, b1, acc[1][1]); \
    acc[2][0] = MF(n##2, b0, acc[2][0]); acc[2][1] = MF(n##2, b1, acc[2][1]); \
    acc[3][0] = MF(n##3, b0, acc[3][0]); acc[3][1] = MF(n##3, b1, acc[3][1]); \
    __builtin_amdgcn_s_setprio(0); }

// ---------------------------------------------------------------------------
// Weight pre-conversion into ONE linear blob per model: 26 chunks x 4096 B.
// chunk c<16: proj skt_c; c>=16: hidden layer (c-16)>>1, s=(c-16)&1 with the
// baked pi permutation (register-chained hidden layers, as round 11).
// Chunk byte layout: [g 4][icf 4][lrow 16][t 8] x 2B.
// ---------------------------------------------------------------------------
__global__ void dg_convert(const float* __restrict__ W_in,
                           const float* __restrict__ W_h,
                           short* __restrict__ wsb) {
    int idx = blockIdx.x * 256 + threadIdx.x;
    if (idx >= NMODEL * CHUNKS * 2048) return;
    int t    = idx & 7;
    int lrow = (idx >> 3) & 15;
    int icf  = (idx >> 7) & 3;
    int g    = (idx >> 9) & 3;
    int mc   = idx >> 11;
    int c    = mc % CHUNKS;
    int m    = mc / CHUNKS;
    int hout = icf * 16 + lrow;
    float v;
    if (c < 16) {
        int k = (c * 4 + g) * 8 + t;
        v = (k < DIN) ? W_in[((size_t)m * DIN + k) * HID + hout] : 0.f;
    } else {
        int l = (c - 16) >> 1, s = (c - 16) & 1;
        int kb = 4 * s + g;
        int pk = 16 * (2 * (kb >> 2) + (t >> 2)) + 4 * (kb & 3) + (t & 3);
        v = W_h[((size_t)(m * NLAY + l) * HID + pk) * HID + hout];
    }
    size_t off = (size_t)m * (CHUNKS * 2048) + c * 2048 + g * 512 +
                 icf * 128 + lrow * 8 + t;
    wsb[off] = bf16r(v);
}

// ---------------------------------------------------------------------------
// Fused kernel with an explicit depth-1 counted-vmcnt weight pipeline (T4).
// Block = 512 threads (8 waves); 64-row x tile in LDS (XOR-swizzled); each
// wave: 32-row half-tile x 6 models, weights walked linearly through the
// blob in 4 KB chunks via inline-asm global_load_dwordx4 into two named
// register buffers. Per step: vmcnt(4) waits ONLY the chunk being consumed,
// leaving the next chunk in flight under the MFMA cluster. Outputs buffered
// in LDS and flushed coalesced (stores never touch vmcnt mid-loop).
// LDS 70 KB -> 2 blocks/CU -> 16 waves/CU (4/SIMD). setprio + bias C-init.
// ---------------------------------------------------------------------------
__global__ __launch_bounds__(512, 4) void dg_main(
    const float* __restrict__ x,
    const short* __restrict__ wsb,
    const float* __restrict__ b_in, const float* __restrict__ b_h,
    const float* __restrict__ W_out, const float* __restrict__ b_out,
    float* __restrict__ out) {

    __shared__ short xs[64 * KP];            // 64 KB
    __shared__ float osb[64 * NMODEL];       // 6 KB output staging

    const int tid  = threadIdx.x;
    const int lane = tid & 63;
    const int w    = tid >> 6;               // wave 0..7
    const int lrow = lane & 15;
    const int g    = lane >> 4;              // lane group 0..3
    const int rowbase = blockIdx.x * 64;
    const int pair = w >> 1;                 // 0..3: model group
    const int hf   = w & 1;                  // row half within the tile
    const int rbase = hf * 32;

    // ---- stage x tile -> LDS as bf16, swizzled, zero-padded k>=495 ----
    for (int i = 0; i < 8; ++i) {
        int r  = i * 8 + w;
        int k0 = lane * 8;
        const float* xr = x + (size_t)(rowbase + r) * DIN + k0;
        uint4v vw;
        if (k0 + 8 <= DIN) {
            f4a a = *(const f4a*)xr;
            f4a b = *(const f4a*)(xr + 4);
            vw[0] = pkbf16(a.v[0], a.v[1]);
            vw[1] = pkbf16(a.v[2], a.v[3]);
            vw[2] = pkbf16(b.v[0], b.v[1]);
            vw[3] = pkbf16(b.v[2], b.v[3]);
        } else {
            float f[8];
#pragma unroll
            for (int j = 0; j < 8; ++j) f[j] = (k0 + j < DIN) ? xr[j] : 0.f;
            vw[0] = pkbf16(f[0], f[1]);
            vw[1] = pkbf16(f[2], f[3]);
            vw[2] = pkbf16(f[4], f[5]);
            vw[3] = pkbf16(f[6], f[7]);
        }
        int byte = (r * (KP * 2) + k0 * 2) ^ ((r & 7) << 4);
        *(short8*)((char*)xs + byte) = __builtin_bit_cast(short8, vw);
    }
    __syncthreads();

    // b_out preload (pre-loop; compiler drains its loads before the loop)
    const float* bop = b_out + pair * 6;
    float bz0 = bop[0], bz1 = bop[1], bz2 = bop[2],
          bz3 = bop[3], bz4 = bop[4], bz5 = bop[5];

    // weight-blob pointer walk (per-lane base; +4096 per chunk)
    const char* pwBase = (const char*)wsb + (size_t)(pair * 6) * MBLOB +
                         g * 1024 + lrow * 16;
    const char* pw = pwBase;
    uint4v w00, w01, w02, w03, w10, w11, w12, w13;
    ISSUE4(w0, pw); pw += 4096;              // chunk 0 in flight
    ISSUE4(w1, pw); pw += 4096;              // chunk 1 in flight

    f32x4 acc[4][2];
    short8 h0b[2][2], hc[2][2];

#pragma unroll 1
    for (int mi = 0; mi < 6; ++mi) {
        const int m = pair * 6 + mi;

        // bias -> C-init (compiler loads; drain-safe)
        const float* bi = b_in + m * HID;
#pragma unroll
        for (int icf = 0; icf < 4; ++icf) {
            f32x4 bv = *(const f32x4*)(bi + icf * 16 + g * 4);
            acc[icf][0] = bv;
            acc[icf][1] = bv;
        }

        // ---------------- projection: 16 chunks, pipelined
#pragma unroll 1
        for (int j = 0; j < 8; ++j) {
            const int se = 2 * j, so = 2 * j + 1;
            short8 be0, be1, bq0, bq1;
            {
                int r0 = rbase + lrow, r1 = rbase + 16 + lrow;
                be0 = *(const short8*)((const char*)xs +
                        ((r0 * (KP * 2) + se * 64 + g * 16) ^ ((r0 & 7) << 4)));
                be1 = *(const short8*)((const char*)xs +
                        ((r1 * (KP * 2) + se * 64 + g * 16) ^ ((r1 & 7) << 4)));
            }
            VW4;                              // chunk se ready (se+1 in flight)
            MM8(w0, be0, be1);
            ISSUE4(w0, pw); pw += 4096;       // chunk se+2
            {
                int r0 = rbase + lrow, r1 = rbase + 16 + lrow;
                bq0 = *(const short8*)((const char*)xs +
                        ((r0 * (KP * 2) + so * 64 + g * 16) ^ ((r0 & 7) << 4)));
                bq1 = *(const short8*)((const char*)xs +
                        ((r1 * (KP * 2) + so * 64 + g * 16) ^ ((r1 & 7) << 4)));
            }
            VW4;                              // chunk so ready
            MM8(w1, bq0, bq1);
            ISSUE4(w1, pw); pw += 4096;       // chunk so+2
        }
        // (consumed c0..c15; c16,c17 = hidden l0 in flight)

        // pack h0 (kept for the residual); hc = layer input
#pragma unroll
        for (int s = 0; s < 2; ++s)
#pragma unroll
            for (int rf = 0; rf < 2; ++rf) {
                h0b[s][rf] = pack2(acc[2 * s][rf], acc[2 * s + 1][rf]);
                hc[s][rf]  = h0b[s][rf];
            }

        // ---------------- 5 hidden layers, pipelined
#pragma unroll 1
        for (int l = 0; l < NLAY; ++l) {
            const float* bh = b_h + (size_t)(m * NLAY + l) * HID;
#pragma unroll
            for (int icf = 0; icf < 4; ++icf) {
                f32x4 bv = *(const f32x4*)(bh + icf * 16 + g * 4);
                acc[icf][0] = bv;
                acc[icf][1] = bv;
            }
            const bool lastC = (mi == 5) && (l == NLAY - 1);
            const char* pA = lastC ? pwBase : pw;            // clamp dummies
            VW4;                              // s0 chunk ready
            MM8(w0, hc[0][0], hc[0][1]);
            ISSUE4(w0, pA); pw += 4096;
            const char* pB = lastC ? (pwBase + 4096) : pw;
            VW4;                              // s1 chunk ready
            MM8(w1, hc[1][0], hc[1][1]);
            ISSUE4(w1, pB); pw += 4096;
            // relu (bias already in accumulator)
#pragma unroll
            for (int icf = 0; icf < 4; ++icf)
#pragma unroll
                for (int rf = 0; rf < 2; ++rf)
#pragma unroll
                    for (int j = 0; j < 4; ++j)
                        acc[icf][rf][j] = fmaxf(acc[icf][rf][j], 0.f);
            if (l != NLAY - 1) {
#pragma unroll
                for (int s = 0; s < 2; ++s)
#pragma unroll
                    for (int rf = 0; rf < 2; ++rf)
                        hc[s][rf] = pack2(acc[2 * s][rf], acc[2 * s + 1][rf]);
            }
        }
        // (next model's c0,c1 in flight)

        // residual: h += h0 (bf16-rounded)
#pragma unroll
        for (int icf = 0; icf < 4; ++icf)
#pragma unroll
            for (int rf = 0; rf < 2; ++rf)
#pragma unroll
                for (int j = 0; j < 4; ++j)
                    acc[icf][rf][j] += bf16f(h0b[icf >> 1][rf][(icf & 1) * 4 + j]);

        // head: dot(h, W_out) + b_out, tanh -> LDS output staging
        const float* wo = W_out + m * HID;
        f32x4 wv0 = *(const f32x4*)(wo + 0 * 16 + g * 4);
        f32x4 wv1 = *(const f32x4*)(wo + 1 * 16 + g * 4);
        f32x4 wv2 = *(const f32x4*)(wo + 2 * 16 + g * 4);
        f32x4 wv3 = *(const f32x4*)(wo + 3 * 16 + g * 4);
        float bo = (mi == 0) ? bz0 : (mi == 1) ? bz1 : (mi == 2) ? bz2 :
                   (mi == 3) ? bz3 : (mi == 4) ? bz4 : bz5;
#pragma unroll
        for (int rf = 0; rf < 2; ++rf) {
            float s = 0.f;
#pragma unroll
            for (int j = 0; j < 4; ++j) {
                s += acc[0][rf][j] * wv0[j];
                s += acc[1][rf][j] * wv1[j];
                s += acc[2][rf][j] * wv2[j];
                s += acc[3][rf][j] * wv3[j];
            }
            s += __shfl_xor(s, 16);
            s += __shfl_xor(s, 32);
            s += bo;
            float e = __expf(2.f * s);
            float o = 1.f - 2.f / (e + 1.f);
            if (g == 0)
                osb[(rbase + rf * 16 + lrow) * NMODEL + m] = o;
        }
    }

    __syncthreads();
    // coalesced flush: 64 rows x 24 models, contiguous in out
    for (int i = tid; i < 64 * NMODEL; i += 512)
        out[(size_t)rowbase * NMODEL + i] = osb[i];
}

extern "C" void kernel_launch(void* const* d_in, const int* in_sizes, int n_in,
                              void* d_out, int out_size, void* d_ws, size_t ws_size,
                              hipStream_t stream) {
    const float* x     = (const float*)d_in[0];
    const float* W_in  = (const float*)d_in[1];
    const float* b_in  = (const float*)d_in[2];
    const float* W_h   = (const float*)d_in[3];
    const float* b_h   = (const float*)d_in[4];
    const float* W_out = (const float*)d_in[5];
    const float* b_out = (const float*)d_in[6];
    float* out = (float*)d_out;

    short* wsb = (short*)d_ws;                   // 24 x 26 x 4096 B = 2.44 MB

    const int N = in_sizes[0] / DIN;             // 65536
    const int CONV = NMODEL * CHUNKS * 2048;     // 1,277,952 elements

    dg_convert<<<(CONV + 255) / 256, 256, 0, stream>>>(W_in, W_h, wsb);
    dg_main<<<N / 64, 512, 0, stream>>>(x, wsb, b_in, b_h, W_out, b_out, out);
}

// Round 18
// 217.112 us; speedup vs baseline: 1.1845x; 1.0051x over previous
//
#include <hip/hip_runtime.h>
#include <hip/hip_bf16.h>

typedef __attribute__((ext_vector_type(8))) short short8;
typedef __attribute__((ext_vector_type(4))) float f32x4;
typedef __attribute__((ext_vector_type(4))) unsigned uint4v;

#define NMODEL 24
#define DIN    495
#define KP     512
#define HID    64
#define NLAY   5

__device__ __forceinline__ short bf16r(float f) {
    unsigned u = __float_as_uint(f);
    u += 0x7fffu + ((u >> 16) & 1u);          // round-to-nearest-even
    return (short)(u >> 16);
}
__device__ __forceinline__ float bf16f(short s) {
    return __uint_as_float(((unsigned)(unsigned short)s) << 16);
}
// packed f32->bf16: one VALU op for two elements (gfx950 v_cvt_pk_bf16_f32)
__device__ __forceinline__ unsigned pkbf16(float lo, float hi) {
    unsigned r;
    asm("v_cvt_pk_bf16_f32 %0, %1, %2" : "=v"(r) : "v"(lo), "v"(hi));
    return r;
}
// pack two f32x4 accumulator fragments into one MFMA B-fragment (short8)
__device__ __forceinline__ short8 pack2(f32x4 a, f32x4 b) {
    uint4v w;
    w[0] = pkbf16(a[0], a[1]);
    w[1] = pkbf16(a[2], a[3]);
    w[2] = pkbf16(b[0], b[1]);
    w[3] = pkbf16(b[2], b[3]);
    return __builtin_bit_cast(short8, w);
}

struct __attribute__((packed, aligned(4))) f4a { float v[4]; };

// ---------------------------------------------------------------------------
// Weight pre-conversion to bf16 in MFMA-fragment-friendly layouts.
//   wib[m][kb][hout][t]  = W_in[m][kb*8+t][hout]          (k padded 495->512)
//   whb[m][l][kb][hout][t] = W_h[m][l][pi(kb,t)][hout]    (pi bakes the C->B
//     lane-group relabeling of the hidden-in axis)
// ---------------------------------------------------------------------------
__global__ void dg_convert(const float* __restrict__ W_in,
                           const float* __restrict__ W_h,
                           short* __restrict__ wib, short* __restrict__ whb) {
    int idx = blockIdx.x * 256 + threadIdx.x;
    if (idx < NMODEL * 64 * HID * 8) {
        int t    = idx & 7;
        int hout = (idx >> 3) & 63;
        int kb   = (idx >> 9) & 63;
        int m    = idx >> 15;
        int k    = kb * 8 + t;
        float v  = (k < DIN) ? W_in[((size_t)m * DIN + k) * HID + hout] : 0.f;
        wib[idx] = bf16r(v);
    }
    if (idx < NMODEL * NLAY * 8 * HID * 8) {
        int t    = idx & 7;
        int hout = (idx >> 3) & 63;
        int kb   = (idx >> 9) & 7;     // kb = 4*s + g
        int ml   = idx >> 12;          // m*5 + l
        int pk   = 16 * (2 * (kb >> 2) + (t >> 2)) + 4 * (kb & 3) + (t & 3);
        float v  = W_h[((size_t)ml * HID + pk) * HID + hout];
        whb[idx] = bf16r(v);
    }
}

// ---------------------------------------------------------------------------
// Fused kernel (round-11 configuration — best verified: 218.7 us bench).
// Block = 512 threads (8 waves), 64 rows of x staged in LDS (bf16,
// XOR-swizzled). Each wave owns a 32-row half-tile (4x2 fragments) and runs
// 6 full models; waves PAIRED on the model index so weight streams merge in
// L1/L2. Occupancy is register-capped at 4 waves/SIMD (~124 unified regs).
// s_setprio(1) around each MFMA cluster decorrelates the wave convoy
// (isolated +2.5%, r11). Bias post-add (r3 numerics, absmax 5.86e-3).
// 64KB LDS -> 2 blocks/CU -> 16 waves/CU (4/SIMD).
// ---------------------------------------------------------------------------
__global__ __launch_bounds__(512, 4) void dg_main(
    const float* __restrict__ x,
    const short* __restrict__ wib, const short* __restrict__ whb,
    const float* __restrict__ b_in, const float* __restrict__ b_h,
    const float* __restrict__ W_out, const float* __restrict__ b_out,
    float* __restrict__ out) {

    __shared__ short xs[64 * KP];            // 64 KB

    const int tid  = threadIdx.x;
    const int lane = tid & 63;
    const int w    = tid >> 6;               // wave 0..7
    const int lrow = lane & 15;
    const int g    = lane >> 4;              // lane group 0..3
    const int rowbase = blockIdx.x * 64;
    const int pair = w >> 1;                 // 0..3: model group
    const int hf   = w & 1;                  // row half within the tile
    const int rbase = hf * 32;

    // ---- stage x tile -> LDS as bf16, swizzled, zero-padded k>=495 ----
    for (int i = 0; i < 8; ++i) {
        int r  = i * 8 + w;
        int k0 = lane * 8;
        const float* xr = x + (size_t)(rowbase + r) * DIN + k0;
        uint4v vw;
        if (k0 + 8 <= DIN) {                 // lanes 0..60: fast vector path
            f4a a = *(const f4a*)xr;
            f4a b = *(const f4a*)(xr + 4);
            vw[0] = pkbf16(a.v[0], a.v[1]);
            vw[1] = pkbf16(a.v[2], a.v[3]);
            vw[2] = pkbf16(b.v[0], b.v[1]);
            vw[3] = pkbf16(b.v[2], b.v[3]);
        } else {                             // lanes 61..63: guarded tail
            float f[8];
#pragma unroll
            for (int j = 0; j < 8; ++j) f[j] = (k0 + j < DIN) ? xr[j] : 0.f;
            vw[0] = pkbf16(f[0], f[1]);
            vw[1] = pkbf16(f[2], f[3]);
            vw[2] = pkbf16(f[4], f[5]);
            vw[3] = pkbf16(f[6], f[7]);
        }
        int byte = (r * (KP * 2) + k0 * 2) ^ ((r & 7) << 4);
        *(short8*)((char*)xs + byte) = __builtin_bit_cast(short8, vw);
    }
    __syncthreads();

    // ---- 6 models per wave (paired across row halves), no further sync ----
#pragma unroll 1
    for (int mi = 0; mi < 6; ++mi) {
        const int m = pair * 6 + mi;

        // ---------------- input projection: C[hout 64][row 32], K = 512
        f32x4 acc[4][2];                      // [icf(hout/16)][rf(row/16)]
#pragma unroll
        for (int a = 0; a < 4; ++a)
#pragma unroll
            for (int b = 0; b < 2; ++b) acc[a][b] = (f32x4)0.0f;

        const short8* wA = (const short8*)wib + (size_t)m * 64 * 64;
#pragma unroll 2
        for (int skt = 0; skt < 16; ++skt) {
            const int kb = skt * 4 + g;
            short8 afr[4], bfr[2];
#pragma unroll
            for (int icf = 0; icf < 4; ++icf)
                afr[icf] = wA[(size_t)kb * 64 + icf * 16 + lrow];
#pragma unroll
            for (int rf = 0; rf < 2; ++rf) {
                int r = rbase + rf * 16 + lrow;
                int byte = (r * (KP * 2) + skt * 64 + g * 16) ^ ((r & 7) << 4);
                bfr[rf] = *(const short8*)((const char*)xs + byte);
            }
            __builtin_amdgcn_s_setprio(1);
#pragma unroll
            for (int icf = 0; icf < 4; ++icf)
#pragma unroll
                for (int rf = 0; rf < 2; ++rf)
                    acc[icf][rf] = __builtin_amdgcn_mfma_f32_16x16x32_bf16(
                        afr[icf], bfr[rf], acc[icf][rf], 0, 0, 0);
            __builtin_amdgcn_s_setprio(0);
        }

        // + b_in  (h0 is NOT relu'd)
        const float* bi = b_in + m * HID;
#pragma unroll
        for (int icf = 0; icf < 4; ++icf) {
            f32x4 bv = *(const f32x4*)(bi + icf * 16 + g * 4);
#pragma unroll
            for (int rf = 0; rf < 2; ++rf) acc[icf][rf] += bv;
        }

        // pack h0 into B-fragments (also kept for the residual)
        short8 h0b[2][2];                     // [s][rf]
#pragma unroll
        for (int s = 0; s < 2; ++s)
#pragma unroll
            for (int rf = 0; rf < 2; ++rf)
                h0b[s][rf] = pack2(acc[2 * s][rf], acc[2 * s + 1][rf]);

        // ---------------- 5 hidden layers, all in registers
        const short8* wH = (const short8*)whb + (size_t)m * NLAY * 8 * 64;
        short8 hc[2][2];
#pragma unroll
        for (int s = 0; s < 2; ++s)
#pragma unroll
            for (int rf = 0; rf < 2; ++rf) hc[s][rf] = h0b[s][rf];

        f32x4 hacc[4][2];
#pragma unroll 1
        for (int l = 0; l < NLAY; ++l) {
#pragma unroll
            for (int a = 0; a < 4; ++a)
#pragma unroll
                for (int b = 0; b < 2; ++b) hacc[a][b] = (f32x4)0.0f;
#pragma unroll
            for (int s = 0; s < 2; ++s) {
                const int kb = 4 * s + g;
                short8 afr[4];
#pragma unroll
                for (int icf = 0; icf < 4; ++icf)
                    afr[icf] = wH[(size_t)(l * 8 + kb) * 64 + icf * 16 + lrow];
                __builtin_amdgcn_s_setprio(1);
#pragma unroll
                for (int icf = 0; icf < 4; ++icf)
#pragma unroll
                    for (int rf = 0; rf < 2; ++rf)
                        hacc[icf][rf] = __builtin_amdgcn_mfma_f32_16x16x32_bf16(
                            afr[icf], hc[s][rf], hacc[icf][rf], 0, 0, 0);
                __builtin_amdgcn_s_setprio(0);
            }
            // bias + relu
            const float* bh = b_h + (size_t)(m * NLAY + l) * HID;
#pragma unroll
            for (int icf = 0; icf < 4; ++icf) {
                f32x4 bv = *(const f32x4*)(bh + icf * 16 + g * 4);
#pragma unroll
                for (int rf = 0; rf < 2; ++rf)
#pragma unroll
                    for (int j = 0; j < 4; ++j)
                        hacc[icf][rf][j] = fmaxf(hacc[icf][rf][j] + bv[j], 0.f);
            }
            if (l != NLAY - 1) {
#pragma unroll
                for (int s = 0; s < 2; ++s)
#pragma unroll
                    for (int rf = 0; rf < 2; ++rf)
                        hc[s][rf] = pack2(hacc[2 * s][rf], hacc[2 * s + 1][rf]);
            }
        }

        // ---------------- residual: h += h0 (bf16-rounded h0, ~2^-9 rel err)
#pragma unroll
        for (int icf = 0; icf < 4; ++icf)
#pragma unroll
            for (int rf = 0; rf < 2; ++rf)
#pragma unroll
                for (int j = 0; j < 4; ++j)
                    hacc[icf][rf][j] += bf16f(h0b[icf >> 1][rf][(icf & 1) * 4 + j]);

        // ---------------- head: dot(h, W_out) + b_out, tanh, store
        const float* wo = W_out + m * HID;
        const float bo = b_out[m];
#pragma unroll
        for (int rf = 0; rf < 2; ++rf) {
            float s = 0.f;
#pragma unroll
            for (int icf = 0; icf < 4; ++icf) {
                f32x4 wv = *(const f32x4*)(wo + icf * 16 + g * 4);
#pragma unroll
                for (int j = 0; j < 4; ++j)
                    s += hacc[icf][rf][j] * wv[j];
            }
            s += __shfl_xor(s, 16);
            s += __shfl_xor(s, 32);
            s += bo;
            float e = __expf(2.f * s);                 // overflow-safe tanh
            float o = 1.f - 2.f / (e + 1.f);
            if (g == 0)
                out[(size_t)(rowbase + rbase + rf * 16 + lrow) * NMODEL + m] = o;
        }
    }
}

extern "C" void kernel_launch(void* const* d_in, const int* in_sizes, int n_in,
                              void* d_out, int out_size, void* d_ws, size_t ws_size,
                              hipStream_t stream) {
    const float* x     = (const float*)d_in[0];
    const float* W_in  = (const float*)d_in[1];
    const float* b_in  = (const float*)d_in[2];
    const float* W_h   = (const float*)d_in[3];
    const float* b_h   = (const float*)d_in[4];
    const float* W_out = (const float*)d_in[5];
    const float* b_out = (const float*)d_in[6];
    float* out = (float*)d_out;

    short* wib = (short*)d_ws;                       // 24*64*64*8 bf16 = 1.5 MB
    short* whb = wib + NMODEL * 64 * HID * 8;        // 24*5*8*64*8 bf16 = 0.94 MB

    const int N = in_sizes[0] / DIN;                 // 65536

    dg_convert<<<3072, 256, 0, stream>>>(W_in, W_h, wib, whb);
    dg_main<<<N / 64, 512, 0, stream>>>(x, wib, whb, b_in, b_h, W_out, b_out, out);
}